// Round 5
// baseline (796.614 us; speedup 1.0000x reference)
//
#include <hip/hip_runtime.h>
#include <hip/hip_bf16.h>

#define N_NODES 20000
#define F_DIM 128
#define D_DIM 64
#define B_GR 8
#define E_EDGES 320000
#define A_ACT 512
#define NI_L 16
#define NCLS 16
#define SCAT_W 4          // scatter row-windows (5000 nodes each)

typedef __hip_bfloat16 bf16;
typedef unsigned long long ull;

// ---- input_message = nf @ w_n2l + bias; also h0b = bf16(relu(im)) ----
__global__ __launch_bounds__(256) void k_n2l(const float* __restrict__ nf,
        const float* __restrict__ w, const float* __restrict__ bias,
        float* __restrict__ im, bf16* __restrict__ h0b) {
    __shared__ float Wl[F_DIM * D_DIM];             // 32 KB
    for (int i = threadIdx.x; i < F_DIM * D_DIM; i += 256) Wl[i] = w[i];
    __syncthreads();
    int lane = threadIdx.x & 63;
    int wid = (blockIdx.x * 256 + threadIdx.x) >> 6;
    int nw  = (gridDim.x * 256) >> 6;
    float b = bias[lane];
    for (int n = wid; n < N_NODES; n += nw) {
        const float* nfr = nf + (size_t)n * F_DIM;
        float acc = b;
        #pragma unroll 8
        for (int k = 0; k < F_DIM; ++k)
            acc = fmaf(nfr[k], Wl[k * D_DIM + lane], acc);
        im[n * D_DIM + lane] = acc;
        h0b[n * D_DIM + lane] = __float2bfloat16(fmaxf(acc, 0.f));
    }
}

// ---------------- CSR build: histogram (XCD-affine) ----------------
__global__ __launch_bounds__(256) void k_hist(const int* __restrict__ rows,
        int* __restrict__ cnt) {
    int g = blockIdx.x & 7;
    int chunk = blockIdx.x >> 3;
    int nb = gridDim.x >> 3;
    int per = (E_EDGES + nb - 1) / nb;
    int e0 = chunk * per, e1 = min(e0 + per, E_EDGES);
    const int* rg = rows + (size_t)g * E_EDGES;
    int* cg = cnt + g * N_NODES;
    for (int e = e0 + (int)threadIdx.x; e < e1; e += 256)
        atomicAdd(&cg[__builtin_nontemporal_load(rg + e)], 1);
}

// ---------------- CSR build: per-graph exclusive scan ----------------
__global__ __launch_bounds__(1024) void k_scan(const int* __restrict__ cnt,
        int* __restrict__ ptr, int* __restrict__ cur) {
    int g = blockIdx.x;
    __shared__ int part[1024];
    int t = threadIdx.x;
    int loc[20];
    int sum = 0;
    #pragma unroll
    for (int i = 0; i < 20; ++i) {
        int idx = t * 20 + i;
        loc[i] = sum;
        if (idx < N_NODES) sum += cnt[g * N_NODES + idx];
    }
    part[t] = sum;
    __syncthreads();
    for (int off = 1; off < 1024; off <<= 1) {
        int v = (t >= off) ? part[t - off] : 0;
        __syncthreads();
        part[t] += v;
        __syncthreads();
    }
    int excl = part[t] - sum;
    #pragma unroll
    for (int i = 0; i < 20; ++i) {
        int idx = t * 20 + i;
        if (idx < N_NODES) {
            int v = excl + loc[i];
            ptr[g * (N_NODES + 1) + idx] = v;
            cur[g * N_NODES + idx] = v;
        }
    }
    if (t == 0) ptr[g * (N_NODES + 1) + N_NODES] = part[1023];
}

// ---- CSR scatter, row-windowed so cw writes merge in L2 before writeback --
__global__ __launch_bounds__(256) void k_scatter(const int* __restrict__ rows,
        const int* __restrict__ cols, const float* __restrict__ ew,
        int* __restrict__ cur, float2* __restrict__ cw) {
    int g = blockIdx.x & 7;
    int chunk = blockIdx.x >> 3;
    int nb = gridDim.x >> 3;
    int per = (E_EDGES + nb - 1) / nb;
    int e0 = chunk * per, e1 = min(e0 + per, E_EDGES);
    const int*   rg = rows + (size_t)g * E_EDGES;
    const int*   cg = cols + (size_t)g * E_EDGES;
    const float* wg = ew   + (size_t)g * E_EDGES;
    int* curg = cur + g * N_NODES;
    float2* cwg = cw + (size_t)g * E_EDGES;
    const int WIN = N_NODES / SCAT_W;               // 5000
    for (int w = 0; w < SCAT_W; ++w) {
        int lo = w * WIN, hi = lo + WIN;
        for (int e = e0 + (int)threadIdx.x; e < e1; e += 256) {
            int r = __builtin_nontemporal_load(rg + e);
            if (r >= lo && r < hi) {
                int   c  = __builtin_nontemporal_load(cg + e);
                float wt = __builtin_nontemporal_load(wg + e);
                int pos = atomicAdd(&curg[r], 1);
                cwg[pos] = make_float2(__int_as_float(c), wt);
            }
        }
    }
}

// ---- fused level: hv[n] = relu( (Σ_e w·src[c]) @ conv_w + conv_b + im[n] )
// src is bf16 (already relu'd / non-negative). 8 graphs, XCD-affine.
template <bool DO_GE, bool STORE_H>
__global__ __launch_bounds__(256) void k_level(const bf16* __restrict__ src,
        size_t src_stride, const int* __restrict__ ptr,
        const float2* __restrict__ cw, const float* __restrict__ im,
        const float* __restrict__ convw, const float* __restrict__ convb,
        bf16* __restrict__ hout, float* __restrict__ ge) {
    __shared__ float sW[D_DIM * D_DIM];             // 16 KB, conv_w
    for (int i = threadIdx.x; i < D_DIM * D_DIM; i += 256) sW[i] = convw[i];
    __syncthreads();
    int lane = threadIdx.x & 63;
    int wv   = threadIdx.x >> 6;
    int g    = blockIdx.x & 7;
    int chunk = blockIdx.x >> 3;
    const int CH = gridDim.x >> 3;
    int waves_per_graph = CH * 4;
    int npw = (N_NODES + waves_per_graph - 1) / waves_per_graph;
    int n0 = (chunk * 4 + wv) * npw;
    int n1 = min(n0 + npw, N_NODES);
    if (n0 >= n1) return;

    float bc = convb[lane];
    const bf16*   sg  = src + (size_t)g * src_stride;
    const int*    pg  = ptr + g * (N_NODES + 1);
    const float2* cwg = cw + (size_t)g * E_EDGES;
    bf16* hg = hout + (size_t)g * N_NODES * D_DIM;
    float gsum = 0.f;

    int s0 = pg[n0];
    for (int n = n0; n < n1; ++n) {
        int s1 = pg[n + 1];
        float imv = __builtin_nontemporal_load(im + n * D_DIM + lane);
        float acc = 0.f;
        int e = s0;
        for (; e + 4 <= s1; e += 4) {                 // 4 independent gathers
            ull u0 = __builtin_nontemporal_load((const ull*)(cwg + e));
            ull u1 = __builtin_nontemporal_load((const ull*)(cwg + e + 1));
            ull u2 = __builtin_nontemporal_load((const ull*)(cwg + e + 2));
            ull u3 = __builtin_nontemporal_load((const ull*)(cwg + e + 3));
            float v0 = __bfloat162float(sg[((int)(u0 & 0xffffffffu) << 6) | lane]);
            float v1 = __bfloat162float(sg[((int)(u1 & 0xffffffffu) << 6) | lane]);
            float v2 = __bfloat162float(sg[((int)(u2 & 0xffffffffu) << 6) | lane]);
            float v3 = __bfloat162float(sg[((int)(u3 & 0xffffffffu) << 6) | lane]);
            acc = fmaf(v0, __int_as_float((int)(u0 >> 32)), acc);
            acc = fmaf(v1, __int_as_float((int)(u1 >> 32)), acc);
            acc = fmaf(v2, __int_as_float((int)(u2 >> 32)), acc);
            acc = fmaf(v3, __int_as_float((int)(u3 >> 32)), acc);
        }
        for (; e < s1; ++e) {
            ull u = __builtin_nontemporal_load((const ull*)(cwg + e));
            float v = __bfloat162float(sg[((int)(u & 0xffffffffu) << 6) | lane]);
            acc = fmaf(v, __int_as_float((int)(u >> 32)), acc);
        }
        s0 = s1;
        float hv = bc;
        #pragma unroll
        for (int k = 0; k < 64; ++k) {
            float pk = __int_as_float(
                __builtin_amdgcn_readlane(__float_as_int(acc), k));
            hv = fmaf(pk, sW[k * 64 + lane], hv);
        }
        hv += imv;
        hv = fmaxf(hv, 0.f);
        if (STORE_H) hg[n * D_DIM + lane] = __float2bfloat16(hv);
        gsum += hv;
    }
    if (DO_GE) atomicAdd(&ge[g * D_DIM + lane], gsum);
}

// ---- recompute level-1 h at the 512 action nodes per graph (1 wave/action)
__global__ __launch_bounds__(256) void k_act(const bf16* __restrict__ h,
        const int* __restrict__ ptr, const float2* __restrict__ cw,
        const float* __restrict__ im, const float* __restrict__ convw,
        const float* __restrict__ convb, const int* __restrict__ actions,
        float* __restrict__ act_emb) {
    __shared__ float sW[D_DIM * D_DIM];
    for (int i = threadIdx.x; i < D_DIM * D_DIM; i += 256) sW[i] = convw[i];
    __syncthreads();
    int lane = threadIdx.x & 63;
    int wv   = threadIdx.x >> 6;
    int g    = blockIdx.y;
    int a    = blockIdx.x * 4 + wv;
    int node = actions[(size_t)g * A_ACT + a];

    const bf16*   sg  = h + (size_t)g * N_NODES * D_DIM;
    const int*    pg  = ptr + g * (N_NODES + 1);
    const float2* cwg = cw + (size_t)g * E_EDGES;
    int s0 = pg[node], s1 = pg[node + 1];
    float acc = 0.f;
    for (int e = s0; e < s1; ++e) {
        ull u = __builtin_nontemporal_load((const ull*)(cwg + e));
        float v = __bfloat162float(sg[((int)(u & 0xffffffffu) << 6) | lane]);
        acc = fmaf(v, __int_as_float((int)(u >> 32)), acc);
    }
    float hv = convb[lane];
    #pragma unroll
    for (int k = 0; k < 64; ++k) {
        float pk = __int_as_float(
            __builtin_amdgcn_readlane(__float_as_int(acc), k));
        hv = fmaf(pk, sW[k * 64 + lane], hv);
    }
    hv += im[node * D_DIM + lane];
    hv = fmaxf(hv, 0.f);
    act_emb[((size_t)g * A_ACT + a) * D_DIM + lane] = hv;
}

// ------- label embed (per graph) + graph_embed mean finalize ----------
__global__ __launch_bounds__(512) void k_small(const int* __restrict__ labels,
        const float* __restrict__ le1w, const float* __restrict__ le1b,
        const float* __restrict__ le2w, const float* __restrict__ le2b,
        float* __restrict__ ge, float* __restrict__ le) {
    int b = threadIdx.x >> 6;
    int lane = threadIdx.x & 63;
    ge[b * D_DIM + lane] *= (1.f / (float)N_NODES);
    float x = le1b[lane];
    #pragma unroll
    for (int i = 0; i < NI_L; ++i) {
        int cls = labels[b * NI_L + i];
        x += le1w[(i * NCLS + cls) * D_DIM + lane];
    }
    x = fmaxf(x, 0.f);
    float acc = le2b[lane];
    for (int hh = 0; hh < D_DIM; ++hh)
        acc = fmaf(__shfl(x, hh), le2w[hh * D_DIM + lane], acc);
    le[b * D_DIM + lane] = fmaxf(acc, 0.f);
}

// ------- raw_pred[b,a] = linout(relu(lin1([ge,le,act]))) -------------
__global__ __launch_bounds__(256) void k_tail(const float* __restrict__ ge,
        const float* __restrict__ le, const float* __restrict__ act_emb,
        const float* __restrict__ lin1w, const float* __restrict__ lin1b,
        const float* __restrict__ loutw, const float* __restrict__ loutb,
        float* __restrict__ raw) {
    __shared__ float Wl[192 * 64];                  // 48 KB
    for (int i = threadIdx.x; i < 192 * 64; i += 256) Wl[i] = lin1w[i];
    __syncthreads();
    int lane = threadIdx.x & 63;
    int wv = blockIdx.x * 4 + (threadIdx.x >> 6);
    if (wv >= B_GR * A_ACT) return;
    int b = wv >> 9;
    float e2 = act_emb[(size_t)wv * D_DIM + lane];
    const float* geb = ge + b * D_DIM;
    const float* leb = le + b * D_DIM;
    float z = lin1b[lane];
    #pragma unroll 4
    for (int k = 0; k < 64; ++k) z = fmaf(geb[k], Wl[k * 64 + lane], z);
    #pragma unroll 4
    for (int k = 0; k < 64; ++k) z = fmaf(leb[k], Wl[(64 + k) * 64 + lane], z);
    #pragma unroll 4
    for (int k = 0; k < 64; ++k) z = fmaf(__shfl(e2, k), Wl[(128 + k) * 64 + lane], z);
    z = fmaxf(z, 0.f);
    float r = z * loutw[lane];
    #pragma unroll
    for (int off = 32; off; off >>= 1) r += __shfl_xor(r, off);
    if (lane == 0) raw[wv] = r + loutb[0];
}

// ---------------- preds[b] = max_a raw[b,a] ----------------
__global__ __launch_bounds__(512) void k_max(const float* __restrict__ raw,
        float* __restrict__ out) {
    int b = threadIdx.x >> 6, lane = threadIdx.x & 63;
    float m = -INFINITY;
    for (int a = lane; a < A_ACT; a += 64) m = fmaxf(m, raw[b * A_ACT + a]);
    #pragma unroll
    for (int off = 32; off; off >>= 1) m = fmaxf(m, __shfl_xor(m, off));
    if (lane == 0) out[b] = m;
}

extern "C" void kernel_launch(void* const* d_in, const int* in_sizes, int n_in,
                              void* d_out, int out_size, void* d_ws, size_t ws_size,
                              hipStream_t stream) {
    const float* nf      = (const float*)d_in[0];
    const float* w_n2l   = (const float*)d_in[1];
    const float* bias_n2l= (const float*)d_in[2];
    const float* conv_w  = (const float*)d_in[3];
    const float* conv_b  = (const float*)d_in[4];
    const float* lin1_w  = (const float*)d_in[5];
    const float* lin1_b  = (const float*)d_in[6];
    const float* linout_w= (const float*)d_in[7];
    const float* linout_b= (const float*)d_in[8];
    const float* le1_w   = (const float*)d_in[9];
    const float* le1_b   = (const float*)d_in[10];
    const float* le2_w   = (const float*)d_in[11];
    const float* le2_b   = (const float*)d_in[12];
    const float* edge_w  = (const float*)d_in[13];
    const int*   rows    = (const int*)d_in[14];
    const int*   cols    = (const int*)d_in[15];
    const int*   labels  = (const int*)d_in[16];
    const int*   actions = (const int*)d_in[17];
    float* out = (float*)d_out;

    const size_t NE = (size_t)N_NODES * D_DIM;      // 1.28 M elems

    // ---- workspace carve (~52 MB; 79.8 MB proven safe) ----
    float2* cw  = (float2*)d_ws;                    // B*E float2 (20.5 MB)
    float* im   = (float*)(cw + (size_t)B_GR * E_EDGES);   // NE f32
    float* act  = im + NE;                          // B*A*D f32
    float* ge   = act + (size_t)B_GR * A_ACT * D_DIM;
    float* le   = ge + 512;
    float* raw  = le + 512;
    int*   cnt  = (int*)(raw + B_GR * A_ACT);
    int*   ptr  = cnt + B_GR * N_NODES;
    int*   cur  = ptr + B_GR * (N_NODES + 1);
    bf16*  h0b  = (bf16*)(cur + B_GR * N_NODES);    // NE bf16 (2.56 MB)
    bf16*  h    = h0b + NE;                         // 8*NE bf16 (20.5 MB)

    // ---- independent prologue ----
    k_n2l<<<512, 256, 0, stream>>>(nf, w_n2l, bias_n2l, im, h0b);
    hipMemsetAsync(cnt, 0, (size_t)B_GR * N_NODES * sizeof(int), stream);
    hipMemsetAsync(ge, 0, 512 * sizeof(float), stream);

    // ---- CSR build (XCD-affine; rows/cols shared by both levels) ----
    k_hist<<<2048, 256, 0, stream>>>(rows, cnt);
    k_scan<<<B_GR, 1024, 0, stream>>>(cnt, ptr, cur);
    k_scatter<<<2048, 256, 0, stream>>>(rows, cols, edge_w, cur, cw);

    // ---- level 0: src = h0b (shared, stride 0), out = h ----
    k_level<false, true><<<192 * 8, 256, 0, stream>>>(
            h0b, 0, ptr, cw, im, conv_w, conv_b, h, nullptr);

    // ---- level 1: src = h, stores nothing, accumulates ge only ----
    k_level<true, false><<<192 * 8, 256, 0, stream>>>(
            h, NE, ptr, cw, im, conv_w, conv_b, nullptr, ge);

    // ---- recompute level-1 h at action nodes ----
    dim3 ga(A_ACT / 4, B_GR);
    k_act<<<ga, 256, 0, stream>>>(h, ptr, cw, im, conv_w, conv_b, actions, act);

    // ---- tail ----
    k_small<<<1, 512, 0, stream>>>(labels, le1_w, le1_b, le2_w, le2_b, ge, le);
    k_tail<<<(B_GR * A_ACT) / 4, 256, 0, stream>>>(ge, le, act, lin1_w, lin1_b,
                                                   linout_w, linout_b, raw);
    k_max<<<1, 512, 0, stream>>>(raw, out);
}

// Round 6
// 683.852 us; speedup vs baseline: 1.1649x; 1.1649x over previous
//
#include <hip/hip_runtime.h>
#include <hip/hip_bf16.h>

#define N_NODES 20000
#define F_DIM 128
#define D_DIM 64
#define B_GR 8
#define E_EDGES 320000
#define A_ACT 512
#define NI_L 16
#define NCLS 16
#define SCAT_W 4          // scatter row-windows (5000 nodes each)

typedef __hip_bfloat16 bf16;

#define REP64(M) \
  M(0) M(1) M(2) M(3) M(4) M(5) M(6) M(7) \
  M(8) M(9) M(10) M(11) M(12) M(13) M(14) M(15) \
  M(16) M(17) M(18) M(19) M(20) M(21) M(22) M(23) \
  M(24) M(25) M(26) M(27) M(28) M(29) M(30) M(31) \
  M(32) M(33) M(34) M(35) M(36) M(37) M(38) M(39) \
  M(40) M(41) M(42) M(43) M(44) M(45) M(46) M(47) \
  M(48) M(49) M(50) M(51) M(52) M(53) M(54) M(55) \
  M(56) M(57) M(58) M(59) M(60) M(61) M(62) M(63)

// ---- input_message = nf @ w_n2l + bias; also h0b = bf16(relu(im)) ----
__global__ __launch_bounds__(256) void k_n2l(const float* __restrict__ nf,
        const float* __restrict__ w, const float* __restrict__ bias,
        float* __restrict__ im, bf16* __restrict__ h0b) {
    __shared__ float Wl[F_DIM * D_DIM];             // 32 KB
    for (int i = threadIdx.x; i < F_DIM * D_DIM; i += 256) Wl[i] = w[i];
    __syncthreads();
    int lane = threadIdx.x & 63;
    int wid = (blockIdx.x * 256 + threadIdx.x) >> 6;
    int nw  = (gridDim.x * 256) >> 6;
    float b = bias[lane];
    for (int n = wid; n < N_NODES; n += nw) {
        const float* nfr = nf + (size_t)n * F_DIM;
        float acc = b;
        #pragma unroll 8
        for (int k = 0; k < F_DIM; ++k)
            acc = fmaf(nfr[k], Wl[k * D_DIM + lane], acc);
        im[n * D_DIM + lane] = acc;
        h0b[n * D_DIM + lane] = __float2bfloat16(fmaxf(acc, 0.f));
    }
}

// ---------------- CSR build: histogram (XCD-affine) ----------------
__global__ __launch_bounds__(256) void k_hist(const int* __restrict__ rows,
        int* __restrict__ cnt) {
    int g = blockIdx.x & 7;
    int chunk = blockIdx.x >> 3;
    int nb = gridDim.x >> 3;
    int per = (E_EDGES + nb - 1) / nb;
    int e0 = chunk * per, e1 = min(e0 + per, E_EDGES);
    const int* rg = rows + (size_t)g * E_EDGES;
    int* cg = cnt + g * N_NODES;
    for (int e = e0 + (int)threadIdx.x; e < e1; e += 256)
        atomicAdd(&cg[rg[e]], 1);
}

// ---------------- CSR build: per-graph exclusive scan ----------------
__global__ __launch_bounds__(1024) void k_scan(const int* __restrict__ cnt,
        int* __restrict__ ptr, int* __restrict__ cur) {
    int g = blockIdx.x;
    __shared__ int part[1024];
    int t = threadIdx.x;
    int loc[20];
    int sum = 0;
    #pragma unroll
    for (int i = 0; i < 20; ++i) {
        int idx = t * 20 + i;
        loc[i] = sum;
        if (idx < N_NODES) sum += cnt[g * N_NODES + idx];
    }
    part[t] = sum;
    __syncthreads();
    for (int off = 1; off < 1024; off <<= 1) {
        int v = (t >= off) ? part[t - off] : 0;
        __syncthreads();
        part[t] += v;
        __syncthreads();
    }
    int excl = part[t] - sum;
    #pragma unroll
    for (int i = 0; i < 20; ++i) {
        int idx = t * 20 + i;
        if (idx < N_NODES) {
            int v = excl + loc[i];
            ptr[g * (N_NODES + 1) + idx] = v;
            cur[g * N_NODES + idx] = v;
        }
    }
    if (t == 0) ptr[g * (N_NODES + 1) + N_NODES] = part[1023];
}

// ---- CSR scatter, row-windowed so cw writes merge in L2 before writeback --
__global__ __launch_bounds__(256) void k_scatter(const int* __restrict__ rows,
        const int* __restrict__ cols, const float* __restrict__ ew,
        int* __restrict__ cur, float2* __restrict__ cw) {
    int g = blockIdx.x & 7;
    int chunk = blockIdx.x >> 3;
    int nb = gridDim.x >> 3;
    int per = (E_EDGES + nb - 1) / nb;
    int e0 = chunk * per, e1 = min(e0 + per, E_EDGES);
    const int*   rg = rows + (size_t)g * E_EDGES;
    const int*   cg = cols + (size_t)g * E_EDGES;
    const float* wg = ew   + (size_t)g * E_EDGES;
    int* curg = cur + g * N_NODES;
    float2* cwg = cw + (size_t)g * E_EDGES;
    const int WIN = N_NODES / SCAT_W;               // 5000
    for (int w = 0; w < SCAT_W; ++w) {
        int lo = w * WIN, hi = lo + WIN;
        for (int e = e0 + (int)threadIdx.x; e < e1; e += 256) {
            int r = __builtin_nontemporal_load(rg + e);
            if (r >= lo && r < hi) {
                int   c  = __builtin_nontemporal_load(cg + e);
                float wt = __builtin_nontemporal_load(wg + e);
                int pos = atomicAdd(&curg[r], 1);
                cwg[pos] = make_float2(__int_as_float(c), wt);
            }
        }
    }
}

// ---- fused level: hv[n] = relu( (Σ_e w·src[c]) @ conv_w + conv_b + im[n] )
// src is bf16 (non-negative). 8 graphs, XCD-affine. conv_w pinned in VGPRs.
template <bool DO_GE, bool STORE_H>
__global__ __launch_bounds__(256) void k_level(const bf16* __restrict__ src,
        size_t src_stride, const int* __restrict__ ptr,
        const float2* __restrict__ cw, const float* __restrict__ im,
        const float* __restrict__ convw, const float* __restrict__ convb,
        bf16* __restrict__ hout, float* __restrict__ ge) {
    int lane = threadIdx.x & 63;
    int wv   = threadIdx.x >> 6;
    int g    = blockIdx.x & 7;
    int chunk = blockIdx.x >> 3;
    const int CH = gridDim.x >> 3;
    int waves_per_graph = CH * 4;
    int npw = (N_NODES + waves_per_graph - 1) / waves_per_graph;
    int n0 = (chunk * 4 + wv) * npw;
    int n1 = min(n0 + npw, N_NODES);
    if (n0 >= n1) return;

    // pin conv_w column (lane) in 64 VGPRs — asm outputs can't be respilled
    #define WDECL(k) float W##k;
    REP64(WDECL)
    #define WLOAD(k) asm volatile("global_load_dword %0, %1, off" \
            : "=v"(W##k) : "v"(convw + (k) * D_DIM + lane));
    REP64(WLOAD)
    asm volatile("s_waitcnt vmcnt(0)" ::: "memory");

    float bc = convb[lane];
    const bf16*   sg  = src + (size_t)g * src_stride;
    const int*    pg  = ptr + g * (N_NODES + 1);
    const float2* cwg = cw + (size_t)g * E_EDGES;
    bf16* hg = hout + (size_t)g * N_NODES * D_DIM;
    float gsum = 0.f;

    int s0 = pg[n0];
    for (int n = n0; n < n1; ++n) {
        int s1 = pg[n + 1];
        float imv = im[n * D_DIM + lane];
        float acc = 0.f;
        int e = s0;
        for (; e + 4 <= s1; e += 4) {                 // 4 independent gathers
            float2 c0 = cwg[e], c1 = cwg[e+1], c2 = cwg[e+2], c3 = cwg[e+3];
            float v0 = __bfloat162float(sg[((size_t)__float_as_int(c0.x) << 6) | lane]);
            float v1 = __bfloat162float(sg[((size_t)__float_as_int(c1.x) << 6) | lane]);
            float v2 = __bfloat162float(sg[((size_t)__float_as_int(c2.x) << 6) | lane]);
            float v3 = __bfloat162float(sg[((size_t)__float_as_int(c3.x) << 6) | lane]);
            acc = fmaf(v0, c0.y, acc);
            acc = fmaf(v1, c1.y, acc);
            acc = fmaf(v2, c2.y, acc);
            acc = fmaf(v3, c3.y, acc);
        }
        for (; e < s1; ++e) {
            float2 cv = cwg[e];
            float v = __bfloat162float(sg[((size_t)__float_as_int(cv.x) << 6) | lane]);
            acc = fmaf(v, cv.y, acc);
        }
        s0 = s1;
        float hv = bc + imv;
        #define WFMA(k) hv = fmaf(__int_as_float( \
                __builtin_amdgcn_readlane(__float_as_int(acc), k)), W##k, hv);
        REP64(WFMA)
        hv = fmaxf(hv, 0.f);
        if (STORE_H) hg[n * D_DIM + lane] = __float2bfloat16(hv);
        gsum += hv;
    }
    if (DO_GE) atomicAdd(&ge[g * D_DIM + lane], gsum);
}

// ---- recompute level-1 h at the 512 action nodes per graph (1 wave/action)
__global__ __launch_bounds__(256) void k_act(const bf16* __restrict__ h,
        const int* __restrict__ ptr, const float2* __restrict__ cw,
        const float* __restrict__ im, const float* __restrict__ convw,
        const float* __restrict__ convb, const int* __restrict__ actions,
        float* __restrict__ act_emb) {
    __shared__ float sW[D_DIM * D_DIM];
    for (int i = threadIdx.x; i < D_DIM * D_DIM; i += 256) sW[i] = convw[i];
    __syncthreads();
    int lane = threadIdx.x & 63;
    int wv   = threadIdx.x >> 6;
    int g    = blockIdx.y;
    int a    = blockIdx.x * 4 + wv;
    int node = actions[(size_t)g * A_ACT + a];

    const bf16*   sg  = h + (size_t)g * N_NODES * D_DIM;
    const int*    pg  = ptr + g * (N_NODES + 1);
    const float2* cwg = cw + (size_t)g * E_EDGES;
    int s0 = pg[node], s1 = pg[node + 1];
    float acc = 0.f;
    for (int e = s0; e < s1; ++e) {
        float2 cv = cwg[e];
        float v = __bfloat162float(sg[((size_t)__float_as_int(cv.x) << 6) | lane]);
        acc = fmaf(v, cv.y, acc);
    }
    float hv = convb[lane] + im[node * D_DIM + lane];
    #pragma unroll
    for (int k = 0; k < 64; ++k) {
        float pk = __int_as_float(
            __builtin_amdgcn_readlane(__float_as_int(acc), k));
        hv = fmaf(pk, sW[k * 64 + lane], hv);
    }
    hv = fmaxf(hv, 0.f);
    act_emb[((size_t)g * A_ACT + a) * D_DIM + lane] = hv;
}

// ------- label embed (per graph) + graph_embed mean finalize ----------
__global__ __launch_bounds__(512) void k_small(const int* __restrict__ labels,
        const float* __restrict__ le1w, const float* __restrict__ le1b,
        const float* __restrict__ le2w, const float* __restrict__ le2b,
        float* __restrict__ ge, float* __restrict__ le) {
    int b = threadIdx.x >> 6;
    int lane = threadIdx.x & 63;
    ge[b * D_DIM + lane] *= (1.f / (float)N_NODES);
    float x = le1b[lane];
    #pragma unroll
    for (int i = 0; i < NI_L; ++i) {
        int cls = labels[b * NI_L + i];
        x += le1w[(i * NCLS + cls) * D_DIM + lane];
    }
    x = fmaxf(x, 0.f);
    float acc = le2b[lane];
    for (int hh = 0; hh < D_DIM; ++hh)
        acc = fmaf(__shfl(x, hh), le2w[hh * D_DIM + lane], acc);
    le[b * D_DIM + lane] = fmaxf(acc, 0.f);
}

// ------- raw_pred[b,a] = linout(relu(lin1([ge,le,act]))) -------------
__global__ __launch_bounds__(256) void k_tail(const float* __restrict__ ge,
        const float* __restrict__ le, const float* __restrict__ act_emb,
        const float* __restrict__ lin1w, const float* __restrict__ lin1b,
        const float* __restrict__ loutw, const float* __restrict__ loutb,
        float* __restrict__ raw) {
    __shared__ float Wl[192 * 64];                  // 48 KB
    for (int i = threadIdx.x; i < 192 * 64; i += 256) Wl[i] = lin1w[i];
    __syncthreads();
    int lane = threadIdx.x & 63;
    int wv = blockIdx.x * 4 + (threadIdx.x >> 6);
    if (wv >= B_GR * A_ACT) return;
    int b = wv >> 9;
    float e2 = act_emb[(size_t)wv * D_DIM + lane];
    const float* geb = ge + b * D_DIM;
    const float* leb = le + b * D_DIM;
    float z = lin1b[lane];
    #pragma unroll 4
    for (int k = 0; k < 64; ++k) z = fmaf(geb[k], Wl[k * 64 + lane], z);
    #pragma unroll 4
    for (int k = 0; k < 64; ++k) z = fmaf(leb[k], Wl[(64 + k) * 64 + lane], z);
    #pragma unroll 4
    for (int k = 0; k < 64; ++k) z = fmaf(__shfl(e2, k), Wl[(128 + k) * 64 + lane], z);
    z = fmaxf(z, 0.f);
    float r = z * loutw[lane];
    #pragma unroll
    for (int off = 32; off; off >>= 1) r += __shfl_xor(r, off);
    if (lane == 0) raw[wv] = r + loutb[0];
}

// ---------------- preds[b] = max_a raw[b,a] ----------------
__global__ __launch_bounds__(512) void k_max(const float* __restrict__ raw,
        float* __restrict__ out) {
    int b = threadIdx.x >> 6, lane = threadIdx.x & 63;
    float m = -INFINITY;
    for (int a = lane; a < A_ACT; a += 64) m = fmaxf(m, raw[b * A_ACT + a]);
    #pragma unroll
    for (int off = 32; off; off >>= 1) m = fmaxf(m, __shfl_xor(m, off));
    if (lane == 0) out[b] = m;
}

extern "C" void kernel_launch(void* const* d_in, const int* in_sizes, int n_in,
                              void* d_out, int out_size, void* d_ws, size_t ws_size,
                              hipStream_t stream) {
    const float* nf      = (const float*)d_in[0];
    const float* w_n2l   = (const float*)d_in[1];
    const float* bias_n2l= (const float*)d_in[2];
    const float* conv_w  = (const float*)d_in[3];
    const float* conv_b  = (const float*)d_in[4];
    const float* lin1_w  = (const float*)d_in[5];
    const float* lin1_b  = (const float*)d_in[6];
    const float* linout_w= (const float*)d_in[7];
    const float* linout_b= (const float*)d_in[8];
    const float* le1_w   = (const float*)d_in[9];
    const float* le1_b   = (const float*)d_in[10];
    const float* le2_w   = (const float*)d_in[11];
    const float* le2_b   = (const float*)d_in[12];
    const float* edge_w  = (const float*)d_in[13];
    const int*   rows    = (const int*)d_in[14];
    const int*   cols    = (const int*)d_in[15];
    const int*   labels  = (const int*)d_in[16];
    const int*   actions = (const int*)d_in[17];
    float* out = (float*)d_out;

    const size_t NE = (size_t)N_NODES * D_DIM;      // 1.28 M elems

    // ---- workspace carve (~52 MB; 79.8 MB proven safe) ----
    float2* cw  = (float2*)d_ws;                    // B*E float2 (20.5 MB)
    float* im   = (float*)(cw + (size_t)B_GR * E_EDGES);   // NE f32
    float* act  = im + NE;                          // B*A*D f32
    float* ge   = act + (size_t)B_GR * A_ACT * D_DIM;
    float* le   = ge + 512;
    float* raw  = le + 512;
    int*   cnt  = (int*)(raw + B_GR * A_ACT);
    int*   ptr  = cnt + B_GR * N_NODES;
    int*   cur  = ptr + B_GR * (N_NODES + 1);
    bf16*  h0b  = (bf16*)(cur + B_GR * N_NODES);    // NE bf16 (2.56 MB)
    bf16*  h    = h0b + NE;                         // 8*NE bf16 (20.5 MB)

    // ---- independent prologue ----
    k_n2l<<<512, 256, 0, stream>>>(nf, w_n2l, bias_n2l, im, h0b);
    hipMemsetAsync(cnt, 0, (size_t)B_GR * N_NODES * sizeof(int), stream);
    hipMemsetAsync(ge, 0, 512 * sizeof(float), stream);

    // ---- CSR build (XCD-affine; rows/cols shared by both levels) ----
    k_hist<<<2048, 256, 0, stream>>>(rows, cnt);
    k_scan<<<B_GR, 1024, 0, stream>>>(cnt, ptr, cur);
    k_scatter<<<2048, 256, 0, stream>>>(rows, cols, edge_w, cur, cw);

    // ---- level 0: src = h0b (shared, stride 0), out = h ----
    k_level<false, true><<<192 * 8, 256, 0, stream>>>(
            h0b, 0, ptr, cw, im, conv_w, conv_b, h, nullptr);

    // ---- level 1: src = h, stores nothing, accumulates ge only ----
    k_level<true, false><<<192 * 8, 256, 0, stream>>>(
            h, NE, ptr, cw, im, conv_w, conv_b, nullptr, ge);

    // ---- recompute level-1 h at action nodes ----
    dim3 ga(A_ACT / 4, B_GR);
    k_act<<<ga, 256, 0, stream>>>(h, ptr, cw, im, conv_w, conv_b, actions, act);

    // ---- tail ----
    k_small<<<1, 512, 0, stream>>>(labels, le1_w, le1_b, le2_w, le2_b, ge, le);
    k_tail<<<(B_GR * A_ACT) / 4, 256, 0, stream>>>(ge, le, act, lin1_w, lin1_b,
                                                   linout_w, linout_b, raw);
    k_max<<<1, 512, 0, stream>>>(raw, out);
}

// Round 7
// 573.552 us; speedup vs baseline: 1.3889x; 1.1923x over previous
//
#include <hip/hip_runtime.h>
#include <hip/hip_bf16.h>

#define N_NODES 20000
#define F_DIM 128
#define D_DIM 64
#define B_GR 8
#define E_EDGES 320000
#define A_ACT 512
#define NI_L 16
#define NCLS 16
#define SCAT_W 2          // scatter row-windows (10000 nodes each)

typedef __hip_bfloat16 bf16;

#define REP64(M) \
  M(0) M(1) M(2) M(3) M(4) M(5) M(6) M(7) \
  M(8) M(9) M(10) M(11) M(12) M(13) M(14) M(15) \
  M(16) M(17) M(18) M(19) M(20) M(21) M(22) M(23) \
  M(24) M(25) M(26) M(27) M(28) M(29) M(30) M(31) \
  M(32) M(33) M(34) M(35) M(36) M(37) M(38) M(39) \
  M(40) M(41) M(42) M(43) M(44) M(45) M(46) M(47) \
  M(48) M(49) M(50) M(51) M(52) M(53) M(54) M(55) \
  M(56) M(57) M(58) M(59) M(60) M(61) M(62) M(63)

// ---- input_message = nf @ w_n2l + bias; also h0b = bf16(relu(im)) ----
__global__ __launch_bounds__(256) void k_n2l(const float* __restrict__ nf,
        const float* __restrict__ w, const float* __restrict__ bias,
        float* __restrict__ im, bf16* __restrict__ h0b) {
    __shared__ float Wl[F_DIM * D_DIM];             // 32 KB
    for (int i = threadIdx.x; i < F_DIM * D_DIM; i += 256) Wl[i] = w[i];
    __syncthreads();
    int lane = threadIdx.x & 63;
    int wid = (blockIdx.x * 256 + threadIdx.x) >> 6;
    int nw  = (gridDim.x * 256) >> 6;
    float b = bias[lane];
    for (int n = wid; n < N_NODES; n += nw) {
        const float* nfr = nf + (size_t)n * F_DIM;
        float acc = b;
        #pragma unroll 8
        for (int k = 0; k < F_DIM; ++k)
            acc = fmaf(nfr[k], Wl[k * D_DIM + lane], acc);
        im[n * D_DIM + lane] = acc;
        h0b[n * D_DIM + lane] = __float2bfloat16(fmaxf(acc, 0.f));
    }
}

// ---------------- CSR build: histogram (XCD-affine) ----------------
__global__ __launch_bounds__(256) void k_hist(const int* __restrict__ rows,
        int* __restrict__ cnt) {
    int g = blockIdx.x & 7;
    int chunk = blockIdx.x >> 3;
    int nb = gridDim.x >> 3;
    int per = (E_EDGES + nb - 1) / nb;
    int e0 = chunk * per, e1 = min(e0 + per, E_EDGES);
    const int* rg = rows + (size_t)g * E_EDGES;
    int* cg = cnt + g * N_NODES;
    for (int e = e0 + (int)threadIdx.x; e < e1; e += 256)
        atomicAdd(&cg[rg[e]], 1);
}

// ---------------- CSR build: per-graph exclusive scan ----------------
__global__ __launch_bounds__(1024) void k_scan(const int* __restrict__ cnt,
        int* __restrict__ ptr, int* __restrict__ cur) {
    int g = blockIdx.x;
    __shared__ int part[1024];
    int t = threadIdx.x;
    int loc[20];
    int sum = 0;
    #pragma unroll
    for (int i = 0; i < 20; ++i) {
        int idx = t * 20 + i;
        loc[i] = sum;
        if (idx < N_NODES) sum += cnt[g * N_NODES + idx];
    }
    part[t] = sum;
    __syncthreads();
    for (int off = 1; off < 1024; off <<= 1) {
        int v = (t >= off) ? part[t - off] : 0;
        __syncthreads();
        part[t] += v;
        __syncthreads();
    }
    int excl = part[t] - sum;
    #pragma unroll
    for (int i = 0; i < 20; ++i) {
        int idx = t * 20 + i;
        if (idx < N_NODES) {
            int v = excl + loc[i];
            ptr[g * (N_NODES + 1) + idx] = v;
            cur[g * N_NODES + idx] = v;
        }
    }
    if (t == 0) ptr[g * (N_NODES + 1) + N_NODES] = part[1023];
}

// ---- CSR scatter, row-windowed so cw writes merge in L2 before writeback --
__global__ __launch_bounds__(256) void k_scatter(const int* __restrict__ rows,
        const int* __restrict__ cols, const float* __restrict__ ew,
        int* __restrict__ cur, float2* __restrict__ cw) {
    int g = blockIdx.x & 7;
    int chunk = blockIdx.x >> 3;
    int nb = gridDim.x >> 3;
    int per = (E_EDGES + nb - 1) / nb;
    int e0 = chunk * per, e1 = min(e0 + per, E_EDGES);
    const int*   rg = rows + (size_t)g * E_EDGES;
    const int*   cg = cols + (size_t)g * E_EDGES;
    const float* wg = ew   + (size_t)g * E_EDGES;
    int* curg = cur + g * N_NODES;
    float2* cwg = cw + (size_t)g * E_EDGES;
    const int WIN = N_NODES / SCAT_W;
    for (int w = 0; w < SCAT_W; ++w) {
        int lo = w * WIN, hi = lo + WIN;
        for (int e = e0 + (int)threadIdx.x; e < e1; e += 256) {
            int r = __builtin_nontemporal_load(rg + e);
            if (r >= lo && r < hi) {
                int   c  = __builtin_nontemporal_load(cg + e);
                float wt = __builtin_nontemporal_load(wg + e);
                int pos = atomicAdd(&curg[r], 1);
                cwg[pos] = make_float2(__int_as_float(c), wt);
            }
        }
    }
}

// ---- fused level: hv[n] = relu( (Σ_e w·src[c]) @ conv_w + conv_b + im[n] )
// src is bf16 (non-negative). 8 graphs, XCD-affine. conv_w pinned in VGPRs.
template <bool DO_GE, bool STORE_H>
__global__ __launch_bounds__(256) void k_level(const bf16* __restrict__ src,
        size_t src_stride, const int* __restrict__ ptr,
        const float2* __restrict__ cw, const float* __restrict__ im,
        const float* __restrict__ convw, const float* __restrict__ convb,
        bf16* __restrict__ hout, float* __restrict__ ge) {
    int lane = threadIdx.x & 63;
    int wv   = threadIdx.x >> 6;
    int g    = blockIdx.x & 7;
    int chunk = blockIdx.x >> 3;
    const int CH = gridDim.x >> 3;
    int waves_per_graph = CH * 4;
    int npw = (N_NODES + waves_per_graph - 1) / waves_per_graph;
    int n0 = (chunk * 4 + wv) * npw;
    int n1 = min(n0 + npw, N_NODES);
    if (n0 >= n1) return;

    // pin conv_w column (lane) in 64 VGPRs
    #define WDECL(k) float W##k;
    REP64(WDECL)
    #define WLOAD(k) asm volatile("global_load_dword %0, %1, off" \
            : "=v"(W##k) : "v"(convw + (k) * D_DIM + lane));
    REP64(WLOAD)
    asm volatile("s_waitcnt vmcnt(0)" ::: "memory");

    float bc = convb[lane];
    const bf16*   sg  = src + (size_t)g * src_stride;
    const int*    pg  = ptr + g * (N_NODES + 1);
    const float2* cwg = cw + (size_t)g * E_EDGES;
    bf16* hg = hout + (size_t)g * N_NODES * D_DIM;
    float gsum = 0.f;

    int s0 = pg[n0];
    for (int n = n0; n < n1; ++n) {
        int s1 = pg[n + 1];
        float imv = im[n * D_DIM + lane];
        float a0 = 0.f, a1 = 0.f, a2 = 0.f, a3 = 0.f;
        int e = s0;
        for (; e + 8 <= s1; e += 8) {                 // 8 outstanding gathers
            float2 c0 = cwg[e],   c1 = cwg[e+1], c2 = cwg[e+2], c3 = cwg[e+3];
            float2 c4 = cwg[e+4], c5 = cwg[e+5], c6 = cwg[e+6], c7 = cwg[e+7];
            float v0 = __bfloat162float(sg[((size_t)__float_as_int(c0.x) << 6) | lane]);
            float v1 = __bfloat162float(sg[((size_t)__float_as_int(c1.x) << 6) | lane]);
            float v2 = __bfloat162float(sg[((size_t)__float_as_int(c2.x) << 6) | lane]);
            float v3 = __bfloat162float(sg[((size_t)__float_as_int(c3.x) << 6) | lane]);
            float v4 = __bfloat162float(sg[((size_t)__float_as_int(c4.x) << 6) | lane]);
            float v5 = __bfloat162float(sg[((size_t)__float_as_int(c5.x) << 6) | lane]);
            float v6 = __bfloat162float(sg[((size_t)__float_as_int(c6.x) << 6) | lane]);
            float v7 = __bfloat162float(sg[((size_t)__float_as_int(c7.x) << 6) | lane]);
            a0 = fmaf(v0, c0.y, a0); a1 = fmaf(v1, c1.y, a1);
            a2 = fmaf(v2, c2.y, a2); a3 = fmaf(v3, c3.y, a3);
            a0 = fmaf(v4, c4.y, a0); a1 = fmaf(v5, c5.y, a1);
            a2 = fmaf(v6, c6.y, a2); a3 = fmaf(v7, c7.y, a3);
        }
        for (; e + 2 <= s1; e += 2) {
            float2 c0 = cwg[e], c1 = cwg[e+1];
            float v0 = __bfloat162float(sg[((size_t)__float_as_int(c0.x) << 6) | lane]);
            float v1 = __bfloat162float(sg[((size_t)__float_as_int(c1.x) << 6) | lane]);
            a0 = fmaf(v0, c0.y, a0); a1 = fmaf(v1, c1.y, a1);
        }
        if (e < s1) {
            float2 cv = cwg[e];
            float v = __bfloat162float(sg[((size_t)__float_as_int(cv.x) << 6) | lane]);
            a2 = fmaf(v, cv.y, a2);
        }
        s0 = s1;
        float acc = (a0 + a1) + (a2 + a3);
        // 4 independent FMA chains (hv[j], j compile-time) break the serial dep
        float hv[4];
        hv[0] = bc + imv; hv[1] = 0.f; hv[2] = 0.f; hv[3] = 0.f;
        #define WFMA(k) hv[(k) >> 4] = fmaf(__int_as_float( \
                __builtin_amdgcn_readlane(__float_as_int(acc), k)), W##k, hv[(k) >> 4]);
        REP64(WFMA)
        float h1 = (hv[0] + hv[1]) + (hv[2] + hv[3]);
        h1 = fmaxf(h1, 0.f);
        if (STORE_H) hg[n * D_DIM + lane] = __float2bfloat16(h1);
        gsum += h1;
    }
    if (DO_GE) atomicAdd(&ge[g * D_DIM + lane], gsum);
}

// ---- recompute level-1 h at the 512 action nodes per graph (1 wave/action)
__global__ __launch_bounds__(256) void k_act(const bf16* __restrict__ h,
        const int* __restrict__ ptr, const float2* __restrict__ cw,
        const float* __restrict__ im, const float* __restrict__ convw,
        const float* __restrict__ convb, const int* __restrict__ actions,
        float* __restrict__ act_emb) {
    __shared__ float sW[D_DIM * D_DIM];
    for (int i = threadIdx.x; i < D_DIM * D_DIM; i += 256) sW[i] = convw[i];
    __syncthreads();
    int lane = threadIdx.x & 63;
    int wv   = threadIdx.x >> 6;
    int g    = blockIdx.y;
    int a    = blockIdx.x * 4 + wv;
    int node = actions[(size_t)g * A_ACT + a];

    const bf16*   sg  = h + (size_t)g * N_NODES * D_DIM;
    const int*    pg  = ptr + g * (N_NODES + 1);
    const float2* cwg = cw + (size_t)g * E_EDGES;
    int s0 = pg[node], s1 = pg[node + 1];
    float acc = 0.f;
    for (int e = s0; e < s1; ++e) {
        float2 cv = cwg[e];
        float v = __bfloat162float(sg[((size_t)__float_as_int(cv.x) << 6) | lane]);
        acc = fmaf(v, cv.y, acc);
    }
    float hv = convb[lane] + im[node * D_DIM + lane];
    #pragma unroll
    for (int k = 0; k < 64; ++k) {
        float pk = __int_as_float(
            __builtin_amdgcn_readlane(__float_as_int(acc), k));
        hv = fmaf(pk, sW[k * 64 + lane], hv);
    }
    hv = fmaxf(hv, 0.f);
    act_emb[((size_t)g * A_ACT + a) * D_DIM + lane] = hv;
}

// ------- label embed (per graph) + graph_embed mean finalize ----------
__global__ __launch_bounds__(512) void k_small(const int* __restrict__ labels,
        const float* __restrict__ le1w, const float* __restrict__ le1b,
        const float* __restrict__ le2w, const float* __restrict__ le2b,
        float* __restrict__ ge, float* __restrict__ le) {
    int b = threadIdx.x >> 6;
    int lane = threadIdx.x & 63;
    ge[b * D_DIM + lane] *= (1.f / (float)N_NODES);
    float x = le1b[lane];
    #pragma unroll
    for (int i = 0; i < NI_L; ++i) {
        int cls = labels[b * NI_L + i];
        x += le1w[(i * NCLS + cls) * D_DIM + lane];
    }
    x = fmaxf(x, 0.f);
    float acc = le2b[lane];
    for (int hh = 0; hh < D_DIM; ++hh)
        acc = fmaf(__shfl(x, hh), le2w[hh * D_DIM + lane], acc);
    le[b * D_DIM + lane] = fmaxf(acc, 0.f);
}

// ------- raw_pred[b,a] = linout(relu(lin1([ge,le,act]))) -------------
__global__ __launch_bounds__(256) void k_tail(const float* __restrict__ ge,
        const float* __restrict__ le, const float* __restrict__ act_emb,
        const float* __restrict__ lin1w, const float* __restrict__ lin1b,
        const float* __restrict__ loutw, const float* __restrict__ loutb,
        float* __restrict__ raw) {
    __shared__ float Wl[192 * 64];                  // 48 KB
    for (int i = threadIdx.x; i < 192 * 64; i += 256) Wl[i] = lin1w[i];
    __syncthreads();
    int lane = threadIdx.x & 63;
    int wv = blockIdx.x * 4 + (threadIdx.x >> 6);
    if (wv >= B_GR * A_ACT) return;
    int b = wv >> 9;
    float e2 = act_emb[(size_t)wv * D_DIM + lane];
    const float* geb = ge + b * D_DIM;
    const float* leb = le + b * D_DIM;
    float z = lin1b[lane];
    #pragma unroll 4
    for (int k = 0; k < 64; ++k) z = fmaf(geb[k], Wl[k * 64 + lane], z);
    #pragma unroll 4
    for (int k = 0; k < 64; ++k) z = fmaf(leb[k], Wl[(64 + k) * 64 + lane], z);
    #pragma unroll 4
    for (int k = 0; k < 64; ++k) z = fmaf(__shfl(e2, k), Wl[(128 + k) * 64 + lane], z);
    z = fmaxf(z, 0.f);
    float r = z * loutw[lane];
    #pragma unroll
    for (int off = 32; off; off >>= 1) r += __shfl_xor(r, off);
    if (lane == 0) raw[wv] = r + loutb[0];
}

// ---------------- preds[b] = max_a raw[b,a] ----------------
__global__ __launch_bounds__(512) void k_max(const float* __restrict__ raw,
        float* __restrict__ out) {
    int b = threadIdx.x >> 6, lane = threadIdx.x & 63;
    float m = -INFINITY;
    for (int a = lane; a < A_ACT; a += 64) m = fmaxf(m, raw[b * A_ACT + a]);
    #pragma unroll
    for (int off = 32; off; off >>= 1) m = fmaxf(m, __shfl_xor(m, off));
    if (lane == 0) out[b] = m;
}

extern "C" void kernel_launch(void* const* d_in, const int* in_sizes, int n_in,
                              void* d_out, int out_size, void* d_ws, size_t ws_size,
                              hipStream_t stream) {
    const float* nf      = (const float*)d_in[0];
    const float* w_n2l   = (const float*)d_in[1];
    const float* bias_n2l= (const float*)d_in[2];
    const float* conv_w  = (const float*)d_in[3];
    const float* conv_b  = (const float*)d_in[4];
    const float* lin1_w  = (const float*)d_in[5];
    const float* lin1_b  = (const float*)d_in[6];
    const float* linout_w= (const float*)d_in[7];
    const float* linout_b= (const float*)d_in[8];
    const float* le1_w   = (const float*)d_in[9];
    const float* le1_b   = (const float*)d_in[10];
    const float* le2_w   = (const float*)d_in[11];
    const float* le2_b   = (const float*)d_in[12];
    const float* edge_w  = (const float*)d_in[13];
    const int*   rows    = (const int*)d_in[14];
    const int*   cols    = (const int*)d_in[15];
    const int*   labels  = (const int*)d_in[16];
    const int*   actions = (const int*)d_in[17];
    float* out = (float*)d_out;

    const size_t NE = (size_t)N_NODES * D_DIM;      // 1.28 M elems

    // ---- workspace carve (~52 MB; 79.8 MB proven safe) ----
    float2* cw  = (float2*)d_ws;                    // B*E float2 (20.5 MB)
    float* im   = (float*)(cw + (size_t)B_GR * E_EDGES);   // NE f32
    float* act  = im + NE;                          // B*A*D f32
    float* ge   = act + (size_t)B_GR * A_ACT * D_DIM;
    float* le   = ge + 512;
    float* raw  = le + 512;
    int*   cnt  = (int*)(raw + B_GR * A_ACT);
    int*   ptr  = cnt + B_GR * N_NODES;
    int*   cur  = ptr + B_GR * (N_NODES + 1);
    bf16*  h0b  = (bf16*)(cur + B_GR * N_NODES);    // NE bf16 (2.56 MB)
    bf16*  h    = h0b + NE;                         // 8*NE bf16 (20.5 MB)

    // ---- independent prologue ----
    k_n2l<<<512, 256, 0, stream>>>(nf, w_n2l, bias_n2l, im, h0b);
    hipMemsetAsync(cnt, 0, (size_t)B_GR * N_NODES * sizeof(int), stream);
    hipMemsetAsync(ge, 0, 512 * sizeof(float), stream);

    // ---- CSR build (XCD-affine; rows/cols shared by both levels) ----
    k_hist<<<2048, 256, 0, stream>>>(rows, cnt);
    k_scan<<<B_GR, 1024, 0, stream>>>(cnt, ptr, cur);
    k_scatter<<<2048, 256, 0, stream>>>(rows, cols, edge_w, cur, cw);

    // ---- level 0: src = h0b (shared, stride 0), out = h ----
    k_level<false, true><<<256 * 8, 256, 0, stream>>>(
            h0b, 0, ptr, cw, im, conv_w, conv_b, h, nullptr);

    // ---- level 1: src = h, stores nothing, accumulates ge only ----
    k_level<true, false><<<256 * 8, 256, 0, stream>>>(
            h, NE, ptr, cw, im, conv_w, conv_b, nullptr, ge);

    // ---- recompute level-1 h at action nodes ----
    dim3 ga(A_ACT / 4, B_GR);
    k_act<<<ga, 256, 0, stream>>>(h, ptr, cw, im, conv_w, conv_b, actions, act);

    // ---- tail ----
    k_small<<<1, 512, 0, stream>>>(labels, le1_w, le1_b, le2_w, le2_b, ge, le);
    k_tail<<<(B_GR * A_ACT) / 4, 256, 0, stream>>>(ge, le, act, lin1_w, lin1_b,
                                                   linout_w, linout_b, raw);
    k_max<<<1, 512, 0, stream>>>(raw, out);
}